// Round 10
// baseline (173.783 us; speedup 1.0000x reference)
//
#include <hip/hip_runtime.h>
#include <hip/hip_fp16.h>

#define PI_F 3.14159265358979323846f

typedef __attribute__((ext_vector_type(8))) _Float16 f16x8;
typedef __attribute__((ext_vector_type(16))) float f32x16;
typedef __attribute__((ext_vector_type(2))) float v2f;

// ---------- packed-fp32 complex helpers (v_pk_fma_f32) ----------
__device__ __forceinline__ v2f pfma(v2f a, v2f b, v2f c) {
    return __builtin_elementwise_fma(a, b, c);
}
__device__ __forceinline__ v2f vswap(v2f a) { return __builtin_shufflevector(a, a, 1, 0); }
__device__ __forceinline__ v2f vsplat(float x) { v2f r; r.x = x; r.y = x; return r; }
__device__ __forceinline__ v2f mkc(v2f u) { v2f r; r.x = -u.y; r.y = u.y; return r; }
__device__ __forceinline__ v2f cmul(v2f a, v2f b) {
    return pfma(mkc(a), vswap(b), vsplat(a.x) * b);
}

__device__ __forceinline__ unsigned f2bf_rn(float x) {
    unsigned u = __float_as_uint(x);
    return (u + 0x7fffu + ((u >> 16) & 1u)) >> 16;
}

union H8 { int4 i4; f16x8 v; };

// async global->LDS, 16B per lane; LDS dest = wave-uniform base + lane*16
__device__ __forceinline__ void gll16(const void* g, void* l) {
    __builtin_amdgcn_global_load_lds(
        (const __attribute__((address_space(1))) void*)g,
        (__attribute__((address_space(3))) void*)l, 16, 0, 0);
}

// ---------------- K1 fused: [blocks 0..255]  encoder -> U3 -> MPS chain -> amp MFMA -> A[b]
//                             [blocks 256..2303] Wd1 conv/transpose -> Wt (k-block-major) ----
// amp(z) = sum_{g,y7} L(z0..z7)[g,y7] * R(z8..z15)[g,y7]  (bond 2 + y0 boundary)
// Wt layout: [kt=256][n=256][kc=256] fp16 -> each conv block writes ONE contiguous 16 KB
// span (R7-R9 falsified LDS-instr/conflict/occupancy theories; 256B-segment writes at
// 128 KB stride were the remaining common factor).
union PreLds {
    struct {
        float xr[64]; float h[128]; float ang[96];
        v2f vL[32];            // a_p: vL[(15-p)*2 + s]
        v2f uL[64];            // G_p: uL[(15-p)*4 + z*2 + y]
        _Float16 lR[256*8];    // R rows (4 KB)
        _Float16 lL[512*8];    // L re-plane rows 0..255, im-plane 256..511 (8 KB)
    } e;
    _Float16 wt[32][258];      // conv tile: 32 n-rows x 256 kc + 2 pad (16.5 KB)
};

__global__ __launch_bounds__(256) void k_pre(
        const float* __restrict__ x, const float* __restrict__ W1,
        const float* __restrict__ b1, const float* __restrict__ W2,
        const float* __restrict__ b2, const float* __restrict__ scaling,
        const float* __restrict__ Wd1, _Float16* __restrict__ Wt,
        _Float16* __restrict__ A) {
    __shared__ PreLds lds;
    const int t = threadIdx.x;
    if (blockIdx.x >= 256) {
        // ---- conv: Wd1 [65536k][256n] fp32 -> Wt [kt][n][kc] fp16 (x64 scale) ----
        // tile 256k x 32n; k-rows paired -> packed half2 ds_write_b32
        const int cb = blockIdx.x - 256;         // 0..2047
        const int kt = cb >> 3;                  // 0..255
        const int nb = (cb & 7) * 32;            // 8 n-tiles
        const int kb = kt * 256;
        unsigned* wtw = (unsigned*)&lds.wt[0][0];   // word view: row stride 129 words
        #pragma unroll
        for (int it = 0; it < 4; ++it) {
            int idx = t + it*256;                // 0..1023
            int kr2 = idx >> 3;                  // k-pair 0..127
            int nc4 = (idx & 7) * 4;             // 0..28
            const float* src = Wd1 + (size_t)(kb + 2*kr2)*256 + nb + nc4;
            float4 w0 = *(const float4*)src;
            float4 w1 = *(const float4*)(src + 256);
            #pragma unroll
            for (int j = 0; j < 4; ++j) {
                float a0 = (j==0?w0.x:j==1?w0.y:j==2?w0.z:w0.w) * 64.f;
                float a1 = (j==0?w1.x:j==1?w1.y:j==2?w1.z:w1.w) * 64.f;
                __half2 hh = __floats2half2_rn(a0, a1);
                unsigned u; __builtin_memcpy(&u, &hh, 4);
                wtw[(nc4 + j)*129 + kr2] = u;
            }
        }
        __syncthreads();
        // write phase: the whole tile is one contiguous 16 KB global span
        _Float16* dst = Wt + (size_t)kt*65536 + (size_t)nb*256;
        #pragma unroll
        for (int it = 0; it < 4; ++it) {
            int idx = t + it*256;                // 0..1023 x 16 B
            int n = idx >> 5, u = idx & 31;
            int4 hh = *(const int4*)&lds.wt[n][u*8];
            *(int4*)(dst + (size_t)n*256 + u*8) = hh;
        }
        return;
    }
    // ---- encoder phase ----
    const int b = blockIdx.x;
    if (t < 64) lds.e.xr[t] = x[b*64 + t];
    __syncthreads();
    if (t < 128) {
        float acc = b1[t];
        #pragma unroll 8
        for (int f = 0; f < 64; ++f) acc = fmaf(lds.e.xr[f], W1[f*128 + t], acc);
        lds.e.h[t] = fmaxf(acc, 0.f);
    }
    __syncthreads();
    if (t < 96) {
        float acc = b2[t];
        #pragma unroll 8
        for (int f = 0; f < 128; ++f) acc = fmaf(lds.e.h[f], W2[f*96 + t], acc);
        int q = (t/3) & 15;
        lds.e.ang[t] = tanhf(acc) * scaling[q] * PI_F;
    }
    __syncthreads();
    if (t < 32) {
        int l = t >> 4, q = t & 15;
        const float* a = lds.e.ang + l*48 + q*3;
        float st, ct, sp, cp, sl, cl;
        sincosf(a[0]*0.5f, &st, &ct);
        sincosf(a[1]*0.5f, &sp, &cp);
        sincosf(a[2]*0.5f, &sl, &cl);
        float2 A00 = make_float2( cp*ct,  sp*st);
        float2 A01 = make_float2(-sp*ct, -cp*st);
        float2 A10 = make_float2( sp*ct, -cp*st);
        float2 A11 = make_float2( cp*ct, -sp*st);
        float2 e0 = make_float2(cl, -sl), e1 = make_float2(cl, sl);
        v2f r00; r00.x = e0.x*A00.x - e0.y*A00.y; r00.y = e0.x*A00.y + e0.y*A00.x;
        v2f r01; r01.x = e0.x*A01.x - e0.y*A01.y; r01.y = e0.x*A01.y + e0.y*A01.x;
        v2f r10; r10.x = e1.x*A10.x - e1.y*A10.y; r10.y = e1.x*A10.y + e1.y*A10.x;
        v2f r11; r11.x = e1.x*A11.x - e1.y*A11.y; r11.y = e1.x*A11.y + e1.y*A11.x;
        if (l == 0) {                 // layer-0: U|0> = column 0
            lds.e.vL[q*2 + 0] = r00;
            lds.e.vL[q*2 + 1] = r10;
        } else {                      // layer-1 gates, row-major
            lds.e.uL[q*4 + 0] = r00; lds.e.uL[q*4 + 1] = r01;
            lds.e.uL[q*4 + 2] = r10; lds.e.uL[q*4 + 3] = r11;
        }
    }
    __syncthreads();
    // ---- chain phase: thread t = prefix (z0..z7) for L, suffix (z8..z15) for R ----
    #define AP(p, s) lds.e.vL[(15-(p))*2 + (s)]
    #define GG(p, zv, yv) lds.e.uL[(15-(p))*4 + (zv)*2 + (yv)]
    const float SL = 32.f;
    v2f Lg[2][2];   // [g][y7]
    {
        int z0 = t & 1, z1 = (t >> 1) & 1;
        #pragma unroll
        for (int g = 0; g < 2; ++g)
            #pragma unroll
            for (int y = 0; y < 2; ++y)
                Lg[g][y] = cmul(cmul(GG(0, z0, g), AP(0, g ^ y)), GG(1, z1, y));
        #pragma unroll
        for (int p = 2; p <= 7; ++p) {
            int zp = (t >> p) & 1;
            #pragma unroll
            for (int g = 0; g < 2; ++g) {
                v2f s0 = cmul(Lg[g][0], AP(p-1, 0)) + cmul(Lg[g][1], AP(p-1, 1));
                v2f s1 = cmul(Lg[g][0], AP(p-1, 1)) + cmul(Lg[g][1], AP(p-1, 0));
                Lg[g][0] = cmul(s0, GG(p, zp, 0));
                Lg[g][1] = cmul(s1, GG(p, zp, 1));
            }
        }
    }
    v2f Rg[2][2];   // [g][y7]
    {
        int z15 = (t >> 7) & 1;
        #pragma unroll
        for (int g = 0; g < 2; ++g)
            #pragma unroll
            for (int y14 = 0; y14 < 2; ++y14)
                Rg[g][y14] = cmul(cmul(AP(14, y14 ^ g),     AP(15, g)),     GG(15, z15, 0))
                           + cmul(cmul(AP(14, y14 ^ 1 ^ g), AP(15, 1 ^ g)), GG(15, z15, 1));
        #pragma unroll
        for (int p = 14; p >= 8; --p) {
            int zp = (t >> (p - 8)) & 1;
            #pragma unroll
            for (int g = 0; g < 2; ++g) {
                v2f t0 = cmul(GG(p, zp, 0), Rg[g][0]);
                v2f t1 = cmul(GG(p, zp, 1), Rg[g][1]);
                v2f n0 = cmul(AP(p-1, 0), t0) + cmul(AP(p-1, 1), t1);
                v2f n1 = cmul(AP(p-1, 1), t0) + cmul(AP(p-1, 0), t1);
                Rg[g][0] = n0; Rg[g][1] = n1;
            }
        }
    }
    #undef AP
    #undef GG
    // ---- pack fp16 rows into LDS: k = g*2 + y7; B-operand signs prebaked ----
    {
        float lre[4] = {Lg[0][0].x, Lg[0][1].x, Lg[1][0].x, Lg[1][1].x};
        float lim[4] = {Lg[0][0].y, Lg[0][1].y, Lg[1][0].y, Lg[1][1].y};
        float rre[4] = {Rg[0][0].x, Rg[0][1].x, Rg[1][0].x, Rg[1][1].x};
        float rim[4] = {Rg[0][0].y, Rg[0][1].y, Rg[1][0].y, Rg[1][1].y};
        H8 hre, him, hr;
        #pragma unroll
        for (int k = 0; k < 4; ++k) {
            hre.v[k]   = (_Float16)(SL * lre[k]);
            hre.v[4+k] = (_Float16)(-SL * lim[k]);
            him.v[k]   = (_Float16)(SL * lim[k]);
            him.v[4+k] = (_Float16)(SL * lre[k]);
            hr.v[k]    = (_Float16)(SL * rre[k]);
            hr.v[4+k]  = (_Float16)(SL * rim[k]);
        }
        *(int4*)&lds.e.lR[t*8]         = hr.i4;
        *(int4*)&lds.e.lL[t*8]         = hre.i4;   // re-plane col
        *(int4*)&lds.e.lL[(256+t)*8]   = him.i4;   // im-plane col
    }
    __syncthreads();
    // ---- amp phase: D[zh][zl|plane] = R @ L^T via MFMA (K=8 padded to 16) ----
    {
        const int wave = t >> 6, lane = t & 63, h2 = lane >> 5, l32 = lane & 31;
        f16x8 zf = {};
        _Float16* Aout = A + ((size_t)b << 16);
        #pragma unroll
        for (int mt2 = 0; mt2 < 2; ++mt2) {
            const int zh0 = (wave*2 + mt2)*32;
            f16x8 af = h2 ? zf : *(const f16x8*)&lds.e.lR[(zh0 + l32)*8];
            #pragma unroll
            for (int j = 0; j < 8; ++j) {
                f16x8 bre = h2 ? zf : *(const f16x8*)&lds.e.lL[(j*32 + l32)*8];
                f16x8 bim = h2 ? zf : *(const f16x8*)&lds.e.lL[(256 + j*32 + l32)*8];
                f32x16 zc = {};
                f32x16 dre = __builtin_amdgcn_mfma_f32_32x32x16_f16(af, bre, zc, 0, 0, 0);
                f32x16 dim = __builtin_amdgcn_mfma_f32_32x32x16_f16(af, bim, zc, 0, 0, 0);
                #pragma unroll
                for (int q = 0; q < 16; ++q) {
                    float p = fmaf(dre[q], dre[q], dim[q]*dim[q]) * 0.00390625f;  // 2^-8
                    int row = zh0 + 4*h2 + (q & 3) + 8*(q >> 2);
                    Aout[row*256 + j*32 + l32] = (_Float16)p;
                }
            }
        }
    }
}

// ---------------- K2: single-pass fp16 MFMA GEMM, split-K, XCD-swizzled ----------------
// partial[ks][m][n] (bf16) = A[m, ks*256:+256] @ WtBlk[ks][n][:]
// tile 128m x 128n x 256k, BK=64; grid 1024 (4 blocks/CU): the 4 (nt,mt) blocks of one
// ks share id%8 -> same XCD -> 2nd read of each A/Wt half is an XCD-L2 hit.
__global__ __launch_bounds__(256, 4) void k_gemm(
        const _Float16* __restrict__ A, const _Float16* __restrict__ Bt,
        unsigned short* __restrict__ partial) {
    __shared__ _Float16 lA[128*64];   // [m][64k], row=128B=8 chunks, chunk c at c^(r&7)
    __shared__ _Float16 lB[128*64];
    const int id = blockIdx.x;
    const int ks = (id & 7) | ((id >> 5) << 3);
    const int p  = (id >> 3) & 3;
    const int nt = p >> 1, mt = p & 1;
    const int k0 = ks*256, n0 = nt*128, m0 = mt*128;
    const int tid = threadIdx.x, wave = tid >> 6, lane = tid & 63;
    const int mw = wave >> 1, nw = wave & 1;
    const int h = lane >> 5, l32 = lane & 31;
    const _Float16* BtK = Bt + (size_t)ks*65536;   // [n][256] block
    f32x16 acc[2][2] = {};
    for (int s = 0; s < 4; ++s) {
        const int kb = k0 + s*64;
        #pragma unroll
        for (int i = 0; i < 4; ++i) {
            int ia = wave*4 + i;
            int r = ia*8 + (lane >> 3);
            int cch = (lane & 7) ^ (r & 7);
            gll16(A   + (size_t)(m0 + r)*65536 + kb + cch*8, &lA[ia*512]);
            gll16(BtK + (size_t)(n0 + r)*256 + s*64 + cch*8, &lB[ia*512]);
        }
        __syncthreads();
        #pragma unroll
        for (int kk = 0; kk < 4; ++kk) {
            const int ch = kk*2 + h;
            f16x8 af[2], bf[2];
            #pragma unroll
            for (int xx = 0; xx < 2; ++xx) {
                int rA = mw*64 + xx*32 + l32;
                af[xx] = *(const f16x8*)&lA[rA*64 + ((ch ^ (rA & 7)) << 3)];
                int rB = nw*64 + xx*32 + l32;
                bf[xx] = *(const f16x8*)&lB[rB*64 + ((ch ^ (rB & 7)) << 3)];
            }
            #pragma unroll
            for (int i = 0; i < 2; ++i)
                #pragma unroll
                for (int jj = 0; jj < 2; ++jj)
                    acc[i][jj] = __builtin_amdgcn_mfma_f32_32x32x16_f16(af[i], bf[jj], acc[i][jj], 0, 0, 0);
        }
        __syncthreads();
    }
    unsigned short* pp = partial + (size_t)ks*65536;
    #pragma unroll
    for (int i = 0; i < 2; ++i) {
        #pragma unroll
        for (int jj = 0; jj < 2; ++jj) {
            int n = n0 + nw*64 + jj*32 + l32;
            int mb = m0 + mw*64 + i*32 + 4*h;
            #pragma unroll
            for (int q = 0; q < 16; ++q) {
                int m = mb + (q & 3) + 8*(q >> 2);
                pp[m*256 + n] = (unsigned short)f2bf_rn(acc[i][jj][q]);
            }
        }
    }
}

// ---------------- K3: fused reduce (256 ks, x 2^-18) + bias + relu + GEMV ----
__global__ __launch_bounds__(256) void k_final(
        const unsigned short* __restrict__ partial, const float* __restrict__ bd1,
        const float* __restrict__ Wd2, const float* __restrict__ bd2,
        float* __restrict__ out) {
    __shared__ float row[256];
    const int m = blockIdx.x, t = threadIdx.x;
    {
        const unsigned short* p = partial + m*256 + t;
        float s = 0.f;
        #pragma unroll 32
        for (int kc = 0; kc < 256; ++kc)
            s += __uint_as_float(((unsigned)p[(size_t)kc*65536]) << 16);
        const float SC = 1.f / 262144.f;   // undo 4096 (A) * 64 (Wt)
        row[t] = fmaxf(fmaf(s, SC, bd1[t]), 0.f);
    }
    __syncthreads();
    if (t < 64) {
        float o = bd2[t];
        #pragma unroll 8
        for (int n = 0; n < 256; ++n) o = fmaf(row[n], Wd2[n*64 + t], o);
        out[m*64 + t] = fmaxf(o, 0.f);
    }
}

extern "C" void kernel_launch(void* const* d_in, const int* in_sizes, int n_in,
                              void* d_out, int out_size, void* d_ws, size_t ws_size,
                              hipStream_t stream) {
    const float* x       = (const float*)d_in[0];
    const float* W1      = (const float*)d_in[1];
    const float* b1      = (const float*)d_in[2];
    const float* W2      = (const float*)d_in[3];
    const float* b2      = (const float*)d_in[4];
    const float* scaling = (const float*)d_in[5];
    const float* Wd1     = (const float*)d_in[6];
    const float* bd1     = (const float*)d_in[7];
    const float* Wd2     = (const float*)d_in[8];
    const float* bd2     = (const float*)d_in[9];
    float* out = (float*)d_out;

    char* ws = (char*)d_ws;
    const size_t MB = 1024*1024;
    _Float16* A  = (_Float16*)(ws + 4*MB);           // 32 MB  [4,36)   A[b][k]
    _Float16* Wt = (_Float16*)(ws + 36*MB);          // 32 MB  [36,68)  Wt[kt][n][kc]
    unsigned short* partial = (unsigned short*)(ws + 68*MB);  // 32 MB [68,100)

    hipLaunchKernelGGL(k_pre, dim3(2304), dim3(256), 0, stream,
                       x, W1, b1, W2, b2, scaling, Wd1, Wt, A);
    hipLaunchKernelGGL(k_gemm, dim3(1024), dim3(256), 0, stream, A, Wt, partial);
    hipLaunchKernelGGL(k_final, dim3(256), dim3(256), 0, stream,
                       partial, bd1, Wd2, bd2, out);
}

// Round 11
// 170.400 us; speedup vs baseline: 1.0199x; 1.0199x over previous
//
#include <hip/hip_runtime.h>
#include <hip/hip_fp16.h>

#define PI_F 3.14159265358979323846f

typedef __attribute__((ext_vector_type(8))) _Float16 f16x8;
typedef __attribute__((ext_vector_type(16))) float f32x16;
typedef __attribute__((ext_vector_type(2))) float v2f;

// ---------- packed-fp32 complex helpers (v_pk_fma_f32) ----------
__device__ __forceinline__ v2f pfma(v2f a, v2f b, v2f c) {
    return __builtin_elementwise_fma(a, b, c);
}
__device__ __forceinline__ v2f vswap(v2f a) { return __builtin_shufflevector(a, a, 1, 0); }
__device__ __forceinline__ v2f vsplat(float x) { v2f r; r.x = x; r.y = x; return r; }
__device__ __forceinline__ v2f mkc(v2f u) { v2f r; r.x = -u.y; r.y = u.y; return r; }
__device__ __forceinline__ v2f cmul(v2f a, v2f b) {
    return pfma(mkc(a), vswap(b), vsplat(a.x) * b);
}

__device__ __forceinline__ unsigned f2bf_rn(float x) {
    unsigned u = __float_as_uint(x);
    return (u + 0x7fffu + ((u >> 16) & 1u)) >> 16;
}

union H8 { int4 i4; unsigned w[4]; f16x8 v; };

// async global->LDS, 16B per lane; LDS dest = wave-uniform base + lane*16
__device__ __forceinline__ void gll16(const void* g, void* l) {
    __builtin_amdgcn_global_load_lds(
        (const __attribute__((address_space(1))) void*)g,
        (__attribute__((address_space(3))) void*)l, 16, 0, 0);
}

// ---------------- K1: encoder -> U3 -> MPS chain -> amp MFMA -> A[b] (fp16, x4096) ----
// amp(z) = sum_{g,y7} L(z0..z7)[g,y7] * R(z8..z15)[g,y7]  (bond 2 + y0 boundary)
struct PreLds {
    float xr[64]; float h[128]; float ang[96];
    v2f vL[32];            // a_p: vL[(15-p)*2 + s]
    v2f uL[64];            // G_p: uL[(15-p)*4 + z*2 + y]
    _Float16 lR[256*8];    // R rows (4 KB)
    _Float16 lL[512*8];    // L re-plane rows 0..255, im-plane 256..511 (8 KB)
};

__global__ __launch_bounds__(256) void k_pre(
        const float* __restrict__ x, const float* __restrict__ W1,
        const float* __restrict__ b1, const float* __restrict__ W2,
        const float* __restrict__ b2, const float* __restrict__ scaling,
        _Float16* __restrict__ A) {
    __shared__ PreLds lds;
    const int t = threadIdx.x;
    const int b = blockIdx.x;
    if (t < 64) lds.xr[t] = x[b*64 + t];
    __syncthreads();
    if (t < 128) {
        float acc = b1[t];
        #pragma unroll 8
        for (int f = 0; f < 64; ++f) acc = fmaf(lds.xr[f], W1[f*128 + t], acc);
        lds.h[t] = fmaxf(acc, 0.f);
    }
    __syncthreads();
    if (t < 96) {
        float acc = b2[t];
        #pragma unroll 8
        for (int f = 0; f < 128; ++f) acc = fmaf(lds.h[f], W2[f*96 + t], acc);
        int q = (t/3) & 15;
        lds.ang[t] = tanhf(acc) * scaling[q] * PI_F;
    }
    __syncthreads();
    if (t < 32) {
        int l = t >> 4, q = t & 15;
        const float* a = lds.ang + l*48 + q*3;
        float st, ct, sp, cp, sl, cl;
        sincosf(a[0]*0.5f, &st, &ct);
        sincosf(a[1]*0.5f, &sp, &cp);
        sincosf(a[2]*0.5f, &sl, &cl);
        float2 A00 = make_float2( cp*ct,  sp*st);
        float2 A01 = make_float2(-sp*ct, -cp*st);
        float2 A10 = make_float2( sp*ct, -cp*st);
        float2 A11 = make_float2( cp*ct, -sp*st);
        float2 e0 = make_float2(cl, -sl), e1 = make_float2(cl, sl);
        v2f r00; r00.x = e0.x*A00.x - e0.y*A00.y; r00.y = e0.x*A00.y + e0.y*A00.x;
        v2f r01; r01.x = e0.x*A01.x - e0.y*A01.y; r01.y = e0.x*A01.y + e0.y*A01.x;
        v2f r10; r10.x = e1.x*A10.x - e1.y*A10.y; r10.y = e1.x*A10.y + e1.y*A10.x;
        v2f r11; r11.x = e1.x*A11.x - e1.y*A11.y; r11.y = e1.x*A11.y + e1.y*A11.x;
        if (l == 0) {                 // layer-0: U|0> = column 0
            lds.vL[q*2 + 0] = r00;
            lds.vL[q*2 + 1] = r10;
        } else {                      // layer-1 gates, row-major
            lds.uL[q*4 + 0] = r00; lds.uL[q*4 + 1] = r01;
            lds.uL[q*4 + 2] = r10; lds.uL[q*4 + 3] = r11;
        }
    }
    __syncthreads();
    // ---- chain phase: thread t = prefix (z0..z7) for L, suffix (z8..z15) for R ----
    #define AP(p, s) lds.vL[(15-(p))*2 + (s)]
    #define GG(p, zv, yv) lds.uL[(15-(p))*4 + (zv)*2 + (yv)]
    const float SL = 32.f;
    v2f Lg[2][2];   // [g][y7]
    {
        int z0 = t & 1, z1 = (t >> 1) & 1;
        #pragma unroll
        for (int g = 0; g < 2; ++g)
            #pragma unroll
            for (int y = 0; y < 2; ++y)
                Lg[g][y] = cmul(cmul(GG(0, z0, g), AP(0, g ^ y)), GG(1, z1, y));
        #pragma unroll
        for (int p = 2; p <= 7; ++p) {
            int zp = (t >> p) & 1;
            #pragma unroll
            for (int g = 0; g < 2; ++g) {
                v2f s0 = cmul(Lg[g][0], AP(p-1, 0)) + cmul(Lg[g][1], AP(p-1, 1));
                v2f s1 = cmul(Lg[g][0], AP(p-1, 1)) + cmul(Lg[g][1], AP(p-1, 0));
                Lg[g][0] = cmul(s0, GG(p, zp, 0));
                Lg[g][1] = cmul(s1, GG(p, zp, 1));
            }
        }
    }
    v2f Rg[2][2];   // [g][y7]
    {
        int z15 = (t >> 7) & 1;
        #pragma unroll
        for (int g = 0; g < 2; ++g)
            #pragma unroll
            for (int y14 = 0; y14 < 2; ++y14)
                Rg[g][y14] = cmul(cmul(AP(14, y14 ^ g),     AP(15, g)),     GG(15, z15, 0))
                           + cmul(cmul(AP(14, y14 ^ 1 ^ g), AP(15, 1 ^ g)), GG(15, z15, 1));
        #pragma unroll
        for (int p = 14; p >= 8; --p) {
            int zp = (t >> (p - 8)) & 1;
            #pragma unroll
            for (int g = 0; g < 2; ++g) {
                v2f t0 = cmul(GG(p, zp, 0), Rg[g][0]);
                v2f t1 = cmul(GG(p, zp, 1), Rg[g][1]);
                v2f n0 = cmul(AP(p-1, 0), t0) + cmul(AP(p-1, 1), t1);
                v2f n1 = cmul(AP(p-1, 1), t0) + cmul(AP(p-1, 0), t1);
                Rg[g][0] = n0; Rg[g][1] = n1;
            }
        }
    }
    #undef AP
    #undef GG
    // ---- pack fp16 rows into LDS: k = g*2 + y7; B-operand signs prebaked ----
    {
        float lre[4] = {Lg[0][0].x, Lg[0][1].x, Lg[1][0].x, Lg[1][1].x};
        float lim[4] = {Lg[0][0].y, Lg[0][1].y, Lg[1][0].y, Lg[1][1].y};
        float rre[4] = {Rg[0][0].x, Rg[0][1].x, Rg[1][0].x, Rg[1][1].x};
        float rim[4] = {Rg[0][0].y, Rg[0][1].y, Rg[1][0].y, Rg[1][1].y};
        H8 hre, him, hr;
        #pragma unroll
        for (int k = 0; k < 4; ++k) {
            hre.v[k]   = (_Float16)(SL * lre[k]);
            hre.v[4+k] = (_Float16)(-SL * lim[k]);
            him.v[k]   = (_Float16)(SL * lim[k]);
            him.v[4+k] = (_Float16)(SL * lre[k]);
            hr.v[k]    = (_Float16)(SL * rre[k]);
            hr.v[4+k]  = (_Float16)(SL * rim[k]);
        }
        *(int4*)&lds.lR[t*8]         = hr.i4;
        *(int4*)&lds.lL[t*8]         = hre.i4;   // re-plane col
        *(int4*)&lds.lL[(256+t)*8]   = him.i4;   // im-plane col
    }
    __syncthreads();
    // ---- amp phase: D[zh][zl|plane] = R @ L^T via MFMA (K=8 padded to 16) ----
    {
        const int wave = t >> 6, lane = t & 63, h2 = lane >> 5, l32 = lane & 31;
        f16x8 zf = {};
        _Float16* Aout = A + ((size_t)b << 16);
        #pragma unroll
        for (int mt2 = 0; mt2 < 2; ++mt2) {
            const int zh0 = (wave*2 + mt2)*32;
            f16x8 af = h2 ? zf : *(const f16x8*)&lds.lR[(zh0 + l32)*8];
            #pragma unroll
            for (int j = 0; j < 8; ++j) {
                f16x8 bre = h2 ? zf : *(const f16x8*)&lds.lL[(j*32 + l32)*8];
                f16x8 bim = h2 ? zf : *(const f16x8*)&lds.lL[(256 + j*32 + l32)*8];
                f32x16 zc = {};
                f32x16 dre = __builtin_amdgcn_mfma_f32_32x32x16_f16(af, bre, zc, 0, 0, 0);
                f32x16 dim = __builtin_amdgcn_mfma_f32_32x32x16_f16(af, bim, zc, 0, 0, 0);
                #pragma unroll
                for (int q = 0; q < 16; ++q) {
                    float p = fmaf(dre[q], dre[q], dim[q]*dim[q]) * 0.00390625f;  // 2^-8
                    int row = zh0 + 4*h2 + (q & 3) + 8*(q >> 2);
                    Aout[row*256 + j*32 + l32] = (_Float16)p;
                }
            }
        }
    }
}

// ---------------- K2: fp16 MFMA GEMM, split-K, B converted from fp32 at point of use ----
// partial[m][ks][n] (bf16) = A[m, ks*256:+256] @ (Wd1[ks*256:+256, n]*64)^T
// tile 128m x 128n x 256k, BK=64; grid 1024; id%8 = ks%8 -> the 4 (nt,mt) blocks of one
// ks share an XCD: Wd1/A tiles read twice hit that XCD's L2.
__global__ __launch_bounds__(256, 3) void k_gemm(
        const _Float16* __restrict__ A, const float* __restrict__ Wd1,
        unsigned short* __restrict__ partial) {
    __shared__ _Float16 lA[128*64];   // [m][64k], row=128B=8 chunks, chunk c at c^(r&7)
    __shared__ float lB[64*128];      // [k][n] fp32, straight
    const int id = blockIdx.x;
    const int ks = (id & 7) | ((id >> 5) << 3);
    const int p  = (id >> 3) & 3;
    const int nt = p >> 1, mt = p & 1;
    const int k0 = ks*256, n0 = nt*128, m0 = mt*128;
    const int tid = threadIdx.x, wave = tid >> 6, lane = tid & 63;
    const int mw = wave >> 1, nw = wave & 1;
    const int h = lane >> 5, l32 = lane & 31;
    f32x16 acc[2][2] = {};
    for (int s = 0; s < 4; ++s) {
        const int kb = k0 + s*64;
        // A: 16 KB fp16, swizzled chunks
        #pragma unroll
        for (int i = 0; i < 4; ++i) {
            int ia = wave*4 + i;
            int r = ia*8 + (lane >> 3);
            int cch = (lane & 7) ^ (r & 7);
            gll16(A + (size_t)(m0 + r)*65536 + kb + cch*8, &lA[ia*512]);
        }
        // B: 32 KB fp32 [64k][128n], 2 rows per instruction
        #pragma unroll
        for (int i = 0; i < 8; ++i) {
            int ib = wave*8 + i;                  // 0..31
            int kr = ib*2 + (lane >> 5);
            int nc = (lane & 31) * 4;
            gll16(Wd1 + (size_t)(kb + kr)*256 + n0 + nc, &lB[ib*256]);
        }
        __syncthreads();
        #pragma unroll
        for (int kk = 0; kk < 4; ++kk) {
            const int ch = kk*2 + h;
            f16x8 af[2], bf[2];
            #pragma unroll
            for (int xx = 0; xx < 2; ++xx) {
                int rA = mw*64 + xx*32 + l32;
                af[xx] = *(const f16x8*)&lA[rA*64 + ((ch ^ (rA & 7)) << 3)];
            }
            #pragma unroll
            for (int j2 = 0; j2 < 2; ++j2) {
                const int col = nw*64 + j2*32 + l32;
                const float* bp = &lB[(kk*16 + h*8)*128 + col];
                H8 bh;
                #pragma unroll
                for (int d = 0; d < 4; ++d) {
                    float f0 = bp[(2*d)*128]   * 64.f;
                    float f1 = bp[(2*d+1)*128] * 64.f;
                    __half2 hh = __floats2half2_rn(f0, f1);   // RN, k-ascending
                    __builtin_memcpy(&bh.w[d], &hh, 4);
                }
                bf[j2] = bh.v;
            }
            #pragma unroll
            for (int i = 0; i < 2; ++i)
                #pragma unroll
                for (int jj = 0; jj < 2; ++jj)
                    acc[i][jj] = __builtin_amdgcn_mfma_f32_32x32x16_f16(af[i], bf[jj], acc[i][jj], 0, 0, 0);
        }
        __syncthreads();
    }
    // epilogue: C/D layout col=lane&31, row=(reg&3)+8*(reg>>2)+4*(lane>>5); bf16
    #pragma unroll
    for (int i = 0; i < 2; ++i) {
        #pragma unroll
        for (int jj = 0; jj < 2; ++jj) {
            int n = n0 + nw*64 + jj*32 + l32;
            int mb = m0 + mw*64 + i*32 + 4*h;
            #pragma unroll
            for (int q = 0; q < 16; ++q) {
                int m = mb + (q & 3) + 8*(q >> 2);
                partial[((size_t)m*256 + ks)*256 + n] = (unsigned short)f2bf_rn(acc[i][jj][q]);
            }
        }
    }
}

// ---------------- K3: reduce (x 2^-18) + bias + relu + GEMV; partial[m] is contiguous ----
__global__ __launch_bounds__(256) void k_final(
        const unsigned short* __restrict__ partial, const float* __restrict__ bd1,
        const float* __restrict__ Wd2, const float* __restrict__ bd2,
        float* __restrict__ out) {
    __shared__ float red[8][256];
    __shared__ float row[256];
    const int m = blockIdx.x, t = threadIdx.x;
    const int kgrp = t >> 5, nb8 = (t & 31) * 8;
    const unsigned short* base = partial + ((size_t)m << 16);
    float v[8] = {0.f, 0.f, 0.f, 0.f, 0.f, 0.f, 0.f, 0.f};
    // each thread: 32 ks rows (kgrp + 8j), 8 consecutive n (one int4/row).
    // per wave instruction: 2 adjacent ks rows x 512 B = 1 KB contiguous.
    #pragma unroll 8
    for (int j = 0; j < 32; ++j) {
        int ksr = kgrp + 8*j;
        int4 d = *(const int4*)(base + ksr*256 + nb8);
        unsigned w[4]; __builtin_memcpy(w, &d, 16);
        #pragma unroll
        for (int wd = 0; wd < 4; ++wd) {
            v[2*wd]   += __uint_as_float(w[wd] << 16);
            v[2*wd+1] += __uint_as_float(w[wd] & 0xffff0000u);
        }
    }
    #pragma unroll
    for (int i = 0; i < 8; ++i) red[kgrp][nb8 + i] = v[i];
    __syncthreads();
    {
        float s = 0.f;
        #pragma unroll
        for (int g = 0; g < 8; ++g) s += red[g][t];
        const float SC = 1.f / 262144.f;   // undo 4096 (A) * 64 (B)
        row[t] = fmaxf(fmaf(s, SC, bd1[t]), 0.f);
    }
    __syncthreads();
    if (t < 64) {
        float o = bd2[t];
        #pragma unroll 8
        for (int n = 0; n < 256; ++n) o = fmaf(row[n], Wd2[n*64 + t], o);
        out[m*64 + t] = fmaxf(o, 0.f);
    }
}

extern "C" void kernel_launch(void* const* d_in, const int* in_sizes, int n_in,
                              void* d_out, int out_size, void* d_ws, size_t ws_size,
                              hipStream_t stream) {
    const float* x       = (const float*)d_in[0];
    const float* W1      = (const float*)d_in[1];
    const float* b1      = (const float*)d_in[2];
    const float* W2      = (const float*)d_in[3];
    const float* b2      = (const float*)d_in[4];
    const float* scaling = (const float*)d_in[5];
    const float* Wd1     = (const float*)d_in[6];
    const float* bd1     = (const float*)d_in[7];
    const float* Wd2     = (const float*)d_in[8];
    const float* bd2     = (const float*)d_in[9];
    float* out = (float*)d_out;

    char* ws = (char*)d_ws;
    const size_t MB = 1024*1024;
    _Float16* A = (_Float16*)(ws + 4*MB);            // 32 MB  [4,36)   A[b][k] fp16 x4096
    unsigned short* partial = (unsigned short*)(ws + 68*MB);  // 32 MB [68,100)  [m][ks][n] bf16

    hipLaunchKernelGGL(k_pre, dim3(256), dim3(256), 0, stream,
                       x, W1, b1, W2, b2, scaling, A);
    hipLaunchKernelGGL(k_gemm, dim3(1024), dim3(256), 0, stream, A, Wd1, partial);
    hipLaunchKernelGGL(k_final, dim3(256), dim3(256), 0, stream,
                       partial, bd1, Wd2, bd2, out);
}